// Round 1
// baseline (567.540 us; speedup 1.0000x reference)
//
#include <hip/hip_runtime.h>
#include <hip/hip_bf16.h>

// TGCN fused pipeline for MI355X (gfx950).
// Key ideas:
//  * A = softmax(pre*mask) = c_n*1^T + sparse(10/row)  ->  all graph convs are
//    O(N*TOPK*C) via colsum + 10-term gathers. No N^3 anywhere.
//  * Exact replication of jax.random.uniform(key(42)) noise (Threefry-2x32,
//    partitionable path) so top-k tie-breaks match the reference bit-for-bit.
//  * Two-pass top-k: cheap per-row lower bound on the 10th-largest pre, then
//    exact (pre+noise, idx) selection among ~25 candidates only.
//  * Final einsum split into node-part (d<10) and temporal-part (d>=10).

#define NOISE_MODE 0  // 0: partitionable xor(o0,o1) [JAX>=0.5 default]
                      // 1: partitionable, bits = o0 only
                      // 2: original (pre-0.5) split-iota path

constexpr int BS = 16, NN_ = 2048, CIN = 32, OUT = 64, TK = 10;
constexpr int ROWS = BS * NN_;            // 32768
constexpr unsigned TF_HALF = 33554432u;   // 16*2048*2048/2 (original path)

// ---------------- Threefry-2x32 (matches jax._src.prng) ----------------
__device__ __forceinline__ void tf2x32(unsigned x0, unsigned x1,
                                       unsigned& o0, unsigned& o1) {
  const unsigned k0 = 0u, k1 = 42u;              // jax.random.key(42)
  const unsigned ks2 = k0 ^ k1 ^ 0x1BD11BDAu;
#define TF_R(rot) { x0 += x1; x1 = (x1 << rot) | (x1 >> (32 - rot)); x1 ^= x0; }
  x0 += k0; x1 += k1;
  TF_R(13) TF_R(15) TF_R(26) TF_R(6)
  x0 += k1; x1 += ks2 + 1u;
  TF_R(17) TF_R(29) TF_R(16) TF_R(24)
  x0 += ks2; x1 += k0 + 2u;
  TF_R(13) TF_R(15) TF_R(26) TF_R(6)
  x0 += k0; x1 += k1 + 3u;
  TF_R(17) TF_R(29) TF_R(16) TF_R(24)
  x0 += k1; x1 += ks2 + 4u;
  TF_R(13) TF_R(15) TF_R(26) TF_R(6)
  x0 += ks2; x1 += k0 + 5u;
#undef TF_R
  o0 = x0; o1 = x1;
}

__device__ __forceinline__ float noise_val(unsigned flat) {
  unsigned bits;
#if NOISE_MODE == 0
  unsigned o0, o1; tf2x32(0u, flat, o0, o1); bits = o0 ^ o1;
#elif NOISE_MODE == 1
  unsigned o0, o1; tf2x32(0u, flat, o0, o1); bits = o0;
#else
  unsigned o0, o1;
  if (flat < TF_HALF) { tf2x32(flat, flat + TF_HALF, o0, o1); bits = o0; }
  else                { tf2x32(flat - TF_HALF, flat, o0, o1); bits = o1; }
#endif
  float u = __uint_as_float((bits >> 9) | 0x3f800000u) - 1.0f;
  return 0.01f * u;
}

// ---------------- K1: A0 = node_emb @ node_emb^T ----------------
__global__ __launch_bounds__(256) void k_a0(const float* __restrict__ ne,
                                            float* __restrict__ A0) {
  int gid = blockIdx.x * 256 + threadIdx.x;     // 2048*2048
  int n = gid >> 11, m = gid & 2047;
  float acc = 0.f;
  #pragma unroll
  for (int d = 0; d < 10; ++d) acc = fmaf(ne[n * 10 + d], ne[m * 10 + d], acc);
  A0[gid] = acc;
}

// ---------------- K2: per-row top-k -> cinv, idx, w ----------------
__global__ __launch_bounds__(256) void k_topk(const float* __restrict__ A0,
                                              const float* __restrict__ t,
                                              const float* __restrict__ n_t,
                                              const float* __restrict__ p,
                                              float* __restrict__ cinv,
                                              int* __restrict__ idxb,
                                              float* __restrict__ wgt) {
  const int warp = threadIdx.x >> 6, lane = threadIdx.x & 63;
  const int lin = blockIdx.x * 4 + warp;
  const int n = lin >> 4, b = lin & 15;     // n-major: A0 row reused across b
  const int r = (b << 11) | n;              // canonical row id

  __shared__ float candV[4][128];
  __shared__ int   candM[4][128];

  // per-batch scalars (uniform over the row -> don't affect tie-breaks)
  float at = 0.f;
  #pragma unroll
  for (int d = 0; d < 8; ++d) at = fmaf(n_t[b * 8 + d], t[b * 8 + d], at);
  float s = 1.0f + 0.3f * (1.0f / (1.0f + expf(-p[b])));

  // load row, compute pre = relu(s*(a+at)); slot -> m = (slot>>2)*256+lane*4+(slot&3)
  float v[32];
  const float4* row = (const float4*)(A0 + (size_t)n * 2048);
  #pragma unroll
  for (int j = 0; j < 8; ++j) {
    float4 f = row[j * 64 + lane];
    v[j * 4 + 0] = fmaxf(s * (f.x + at), 0.f);
    v[j * 4 + 1] = fmaxf(s * (f.y + at), 0.f);
    v[j * 4 + 2] = fmaxf(s * (f.z + at), 0.f);
    v[j * 4 + 3] = fmaxf(s * (f.w + at), 0.f);
  }

  // lane max
  float lm = -1.f;
  #pragma unroll
  for (int j = 0; j < 32; ++j) lm = fmaxf(lm, v[j]);

  // 11th-largest (distinct) lane-max: lower bound on 11th-largest global value
  float last = 3.4e38f;
  for (int rd = 0; rd < 11; ++rd) {
    float x = (lm < last) ? lm : -1.f;
    #pragma unroll
    for (int off = 32; off > 0; off >>= 1) x = fmaxf(x, __shfl_xor(x, off));
    last = x;
  }
  const float T = last - 0.0101f;   // safe: T < v10 - 0.01 (noise in [0,0.01))

  // collect candidates (compaction via ballot prefix)
  int cnt = 0;
  #pragma unroll
  for (int slot = 0; slot < 32; ++slot) {
    bool c = (v[slot] >= T);
    unsigned long long mk = __ballot(c);
    if (c) {
      int pos = cnt + __popcll(mk & ((1ull << lane) - 1ull));
      if (pos < 128) {
        candV[warp][pos] = v[slot];
        candM[warp][pos] = ((slot >> 2) << 8) + (lane << 2) + (slot & 3);
      }
    }
    cnt += (int)__popcll(mk);
  }
  int C = cnt < 128 ? cnt : 128;
  __syncthreads();

  // exact top-10 of (pre + noise), tie-break by smaller index (lax.top_k)
  float k0 = -1.f, k1v = -1.f, p0 = 0.f, p1 = 0.f;
  int m0 = 1 << 30, m1 = 1 << 30;
  if (lane < C) {
    p0 = candV[warp][lane]; m0 = candM[warp][lane];
    k0 = p0 + noise_val((unsigned)r * 2048u + (unsigned)m0);
  }
  if (lane + 64 < C) {
    p1 = candV[warp][lane + 64]; m1 = candM[warp][lane + 64];
    k1v = p1 + noise_val((unsigned)r * 2048u + (unsigned)m1);
  }

  float selPre = 0.f; int selIdx = 0;
  for (int ts = 0; ts < 10; ++ts) {
    bool first = (k0 > k1v) || (k0 == k1v && m0 < m1);
    float bk = first ? k0 : k1v; int bm = first ? m0 : m1; float bp = first ? p0 : p1;
    #pragma unroll
    for (int off = 32; off > 0; off >>= 1) {
      float ok = __shfl_xor(bk, off); int om = __shfl_xor(bm, off);
      float op = __shfl_xor(bp, off);
      if (ok > bk || (ok == bk && om < bm)) { bk = ok; bm = om; bp = op; }
    }
    if (lane == ts) { selIdx = bm; selPre = bp; }
    if (m0 == bm) k0 = -1.f;
    if (m1 == bm) k1v = -1.f;
  }

  // Z = (2048-10)*exp(0) + sum exp(pre_topk); w_j = (exp(pre_j)-1)/Z
  float e = (lane < 10) ? expf(selPre) : 0.f;
  float sum = e;
  #pragma unroll
  for (int off = 32; off > 0; off >>= 1) sum += __shfl_xor(sum, off);
  float ci = 1.0f / (2038.0f + sum);
  if (lane == 0) cinv[r] = ci;
  if (lane < 10) {
    idxb[r * 10 + lane] = selIdx;
    wgt[r * 10 + lane] = (e - 1.0f) * ci;
  }
}

// ---------------- K3: per-batch column sums [16][32] ----------------
__global__ __launch_bounds__(256) void k_colsum(const float* __restrict__ in,
                                                float* __restrict__ cs) {
  const int b = blockIdx.x, c = threadIdx.x & 31, g = threadIdx.x >> 5;
  double acc = 0.0;
  for (int m = g; m < 2048; m += 8) acc += (double)in[(((b << 11) + m) << 5) + c];
  __shared__ double red[8][32];
  red[g][c] = acc;
  __syncthreads();
  if (g == 0) {
    double s2 = red[0][c];
    #pragma unroll
    for (int i = 1; i < 8; ++i) s2 += red[i][c];
    cs[(b << 5) + c] = (float)s2;
  }
}

// ---------------- K4: Y1 = A@x = cinv*colsum_x + sum w_j x[idx_j] ----------------
__global__ __launch_bounds__(256) void k_axpy(const float* __restrict__ x,
                                              const float* __restrict__ cinv,
                                              const int* __restrict__ idxb,
                                              const float* __restrict__ wgt,
                                              const float* __restrict__ cs,
                                              float* __restrict__ Y1) {
  int gid = blockIdx.x * 256 + threadIdx.x;   // ROWS*32
  int r = gid >> 5, c = gid & 31, b = r >> 11;
  float acc = cinv[r] * cs[(b << 5) + c];
  #pragma unroll
  for (int j = 0; j < 10; ++j)
    acc = fmaf(wgt[r * 10 + j], x[(((b << 11) + idxb[r * 10 + j]) << 5) + c], acc);
  Y1[gid] = acc;
}

// ---------------- K5: Y2 = A@Y1 ; build V = [x, Y1, 2*Y2 - x] ----------------
__global__ __launch_bounds__(256) void k_v(const float* __restrict__ x,
                                           const float* __restrict__ Y1,
                                           const float* __restrict__ cinv,
                                           const int* __restrict__ idxb,
                                           const float* __restrict__ wgt,
                                           const float* __restrict__ csy,
                                           float* __restrict__ V) {
  int gid = blockIdx.x * 256 + threadIdx.x;   // ROWS*32
  int r = gid >> 5, c = gid & 31, b = r >> 11;
  float y2 = cinv[r] * csy[(b << 5) + c];
  #pragma unroll
  for (int j = 0; j < 10; ++j)
    y2 = fmaf(wgt[r * 10 + j], Y1[(((b << 11) + idxb[r * 10 + j]) << 5) + c], y2);
  float xv = x[gid], y1v = Y1[gid];
  V[r * 96 + c] = xv;
  V[r * 96 + 32 + c] = y1v;
  V[r * 96 + 64 + c] = 2.f * y2 - xv;
}

// ---------------- K6: node-term + bias  (2 nodes/block, all 16 batches) ----------------
__global__ __launch_bounds__(256) void k_outn(const float* __restrict__ ne,
                                              const float* __restrict__ n_t,
                                              const float* __restrict__ wp,
                                              const float* __restrict__ bp,
                                              const float* __restrict__ V,
                                              float* __restrict__ out) {
  const int n0 = blockIdx.x * 2;              // 1024 blocks
  __shared__ float Wn[2][96][64];             // 48 KiB
  __shared__ float Vs[2][16][98];             // padded: bg-broadcast conflict-free
  __shared__ float bN[2][64];

  for (int e2 = threadIdx.x; e2 < 2 * 96 * 64; e2 += 256) {
    int nn = e2 / 6144, rem = e2 % 6144, ki = rem >> 6, o = rem & 63;
    float acc = 0.f;
    #pragma unroll
    for (int d = 0; d < 10; ++d)
      acc = fmaf(ne[(n0 + nn) * 10 + d], wp[(d * 96 + ki) * 64 + o], acc);
    Wn[nn][ki][o] = acc;
  }
  for (int e2 = threadIdx.x; e2 < 2 * 16 * 96; e2 += 256) {
    int nn = e2 / 1536, rem = e2 % 1536, bb = rem / 96, ki = rem % 96;
    Vs[nn][bb][ki] = V[((size_t)(bb << 11) + n0 + nn) * 96 + ki];
  }
  for (int e2 = threadIdx.x; e2 < 2 * 64; e2 += 256) {
    int nn = e2 >> 6, o = e2 & 63;
    float acc = 0.f;
    #pragma unroll
    for (int d = 0; d < 10; ++d)
      acc = fmaf(ne[(n0 + nn) * 10 + d], bp[d * 64 + o], acc);
    bN[nn][o] = acc;
  }
  __syncthreads();

  const int wave = threadIdx.x >> 6, lane = threadIdx.x & 63;
  const int nn = wave >> 1, half = wave & 1;
  const int og = lane & 15, bg = lane >> 4;
  const int bA = half * 8 + bg * 2, bB = bA + 1;

  float acc[2][4] = {};
  for (int ki = 0; ki < 96; ++ki) {
    float4 wv = *(const float4*)&Wn[nn][ki][og * 4];
    float vA = Vs[nn][bA][ki], vB = Vs[nn][bB][ki];
    acc[0][0] = fmaf(vA, wv.x, acc[0][0]); acc[0][1] = fmaf(vA, wv.y, acc[0][1]);
    acc[0][2] = fmaf(vA, wv.z, acc[0][2]); acc[0][3] = fmaf(vA, wv.w, acc[0][3]);
    acc[1][0] = fmaf(vB, wv.x, acc[1][0]); acc[1][1] = fmaf(vB, wv.y, acc[1][1]);
    acc[1][2] = fmaf(vB, wv.z, acc[1][2]); acc[1][3] = fmaf(vB, wv.w, acc[1][3]);
  }
  const int n = n0 + nn;
  #pragma unroll
  for (int i = 0; i < 2; ++i) {
    int b = (i == 0) ? bA : bB;
    float4 res;
    #pragma unroll
    for (int q = 0; q < 4; ++q) {
      int o = og * 4 + q;
      float bT = 0.f;
      #pragma unroll
      for (int d = 0; d < 8; ++d)
        bT = fmaf(n_t[b * 8 + d], bp[(10 + d) * 64 + o], bT);
      (&res.x)[q] = acc[i][q] + bN[nn][o] + bT;
    }
    *(float4*)&out[((size_t)(b << 11) + n) * 64 + og * 4] = res;
  }
}

// ---------------- K7: temporal-term  out += V @ Wt[b] ----------------
__global__ __launch_bounds__(256) void k_outt(const float* __restrict__ n_t,
                                              const float* __restrict__ wp,
                                              const float* __restrict__ V,
                                              float* __restrict__ out) {
  const int b = blockIdx.x >> 3, tile = blockIdx.x & 7;   // 128 blocks
  __shared__ float Wt[96][64];
  for (int e2 = threadIdx.x; e2 < 96 * 64; e2 += 256) {
    int ki = e2 >> 6, o = e2 & 63;
    float acc = 0.f;
    #pragma unroll
    for (int d = 0; d < 8; ++d)
      acc = fmaf(n_t[b * 8 + d], wp[((10 + d) * 96 + ki) * 64 + o], acc);
    Wt[ki][o] = acc;
  }
  __syncthreads();
  const int wave = threadIdx.x >> 6, lane = threadIdx.x & 63;
  const int og = lane & 15, rg = lane >> 4;
  const int rowbase = tile * 256 + wave * 64;
  for (int step = 0; step < 4; ++step) {
    int r0 = rowbase + step * 16 + rg * 4;
    float acc[4][4] = {};
    for (int ki4 = 0; ki4 < 24; ++ki4) {
      float4 vv[4];
      #pragma unroll
      for (int i = 0; i < 4; ++i)
        vv[i] = *(const float4*)&V[(size_t)((b << 11) + r0 + i) * 96 + ki4 * 4];
      #pragma unroll
      for (int t2 = 0; t2 < 4; ++t2) {
        float4 wv = *(const float4*)&Wt[ki4 * 4 + t2][og * 4];
        #pragma unroll
        for (int i = 0; i < 4; ++i) {
          float vi = (t2 == 0) ? vv[i].x : (t2 == 1) ? vv[i].y
                   : (t2 == 2) ? vv[i].z : vv[i].w;
          acc[i][0] = fmaf(vi, wv.x, acc[i][0]);
          acc[i][1] = fmaf(vi, wv.y, acc[i][1]);
          acc[i][2] = fmaf(vi, wv.z, acc[i][2]);
          acc[i][3] = fmaf(vi, wv.w, acc[i][3]);
        }
      }
    }
    #pragma unroll
    for (int i = 0; i < 4; ++i) {
      size_t oidx = (size_t)((b << 11) + r0 + i) * 64 + og * 4;
      float4 cur = *(float4*)&out[oidx];
      cur.x += acc[i][0]; cur.y += acc[i][1];
      cur.z += acc[i][2]; cur.w += acc[i][3];
      *(float4*)&out[oidx] = cur;
    }
  }
}

extern "C" void kernel_launch(void* const* d_in, const int* in_sizes, int n_in,
                              void* d_out, int out_size, void* d_ws, size_t ws_size,
                              hipStream_t stream) {
  const float* x   = (const float*)d_in[0];
  const float* ne  = (const float*)d_in[1];
  const float* t   = (const float*)d_in[2];
  const float* n_t = (const float*)d_in[3];
  const float* p   = (const float*)d_in[4];
  const float* wp  = (const float*)d_in[5];
  const float* bp  = (const float*)d_in[6];
  float* out = (float*)d_out;

  // workspace layout (floats): total ~9.08M floats = 36.3 MB
  float* ws   = (float*)d_ws;
  float* A0   = ws;                         // 4,194,304
  float* cinv = A0 + 4194304;               // 32,768
  int*   idxb = (int*)(cinv + 32768);       // 327,680
  float* wgt  = (float*)(idxb + 327680);    // 327,680
  float* csx  = wgt + 327680;               // 512
  float* csy  = csx + 512;                  // 512
  float* Y1   = csy + 512;                  // 1,048,576
  float* V    = Y1 + 1048576;               // 3,145,728

  k_a0  <<<16384, 256, 0, stream>>>(ne, A0);
  k_topk<<<8192, 256, 0, stream>>>(A0, t, n_t, p, cinv, idxb, wgt);
  k_colsum<<<16, 256, 0, stream>>>(x, csx);
  k_axpy<<<4096, 256, 0, stream>>>(x, cinv, idxb, wgt, csx, Y1);
  k_colsum<<<16, 256, 0, stream>>>(Y1, csy);
  k_v   <<<4096, 256, 0, stream>>>(x, Y1, cinv, idxb, wgt, csy, V);
  k_outn<<<1024, 256, 0, stream>>>(ne, n_t, wp, bp, V, out);
  k_outt<<<128, 256, 0, stream>>>(n_t, wp, V, out);
}

// Round 2
// 400.112 us; speedup vs baseline: 1.4185x; 1.4185x over previous
//
#include <hip/hip_runtime.h>
#include <hip/hip_bf16.h>

// TGCN fused pipeline for MI355X (gfx950).
//  * A = softmax(pre*mask) = c_n*1^T + sparse(10/row)  ->  all graph convs are
//    O(N*TOPK*C) via colsum + 10-term gathers. No N^3 anywhere.
//  * Exact Threefry-2x32 replication of jax.random.uniform(key(42)) noise so
//    top-k tie-breaks match the reference bit-for-bit (verified: passed r1).
//  * Two-pass top-k: per-row lower bound on the 10th-largest pre, exact
//    (pre+noise, idx) selection among the ~25 candidates only.
//  * Final einsum split into node-part (d<10, per-node weight, shared over b)
//    and temporal-part (d>=10, per-batch weight, shared over n).
// R2 changes: k_outt regrid 128->512 blocks (was 5.6% occupancy, 210us);
//             k_topk stages A0 row in LDS, 4 batches/warp (16x less L2 traffic);
//             k_outn ki-split halves LDS 61->37.6KB (2->4 blocks/CU).

#define NOISE_MODE 0

constexpr int BS = 16, NN_ = 2048, CIN = 32, OUT = 64, TK = 10;
constexpr int ROWS = BS * NN_;

// ---------------- Threefry-2x32 (matches jax._src.prng) ----------------
__device__ __forceinline__ void tf2x32(unsigned x0, unsigned x1,
                                       unsigned& o0, unsigned& o1) {
  const unsigned k0 = 0u, k1 = 42u;
  const unsigned ks2 = k0 ^ k1 ^ 0x1BD11BDAu;
#define TF_R(rot) { x0 += x1; x1 = (x1 << rot) | (x1 >> (32 - rot)); x1 ^= x0; }
  x0 += k0; x1 += k1;
  TF_R(13) TF_R(15) TF_R(26) TF_R(6)
  x0 += k1; x1 += ks2 + 1u;
  TF_R(17) TF_R(29) TF_R(16) TF_R(24)
  x0 += ks2; x1 += k0 + 2u;
  TF_R(13) TF_R(15) TF_R(26) TF_R(6)
  x0 += k0; x1 += k1 + 3u;
  TF_R(17) TF_R(29) TF_R(16) TF_R(24)
  x0 += k1; x1 += ks2 + 4u;
  TF_R(13) TF_R(15) TF_R(26) TF_R(6)
  x0 += ks2; x1 += k0 + 5u;
#undef TF_R
  o0 = x0; o1 = x1;
}

__device__ __forceinline__ float noise_val(unsigned flat) {
  unsigned o0, o1; tf2x32(0u, flat, o0, o1);
  unsigned bits = o0 ^ o1;
  float u = __uint_as_float((bits >> 9) | 0x3f800000u) - 1.0f;
  return 0.01f * u;
}

// ---------------- K1: A0 = node_emb @ node_emb^T ----------------
__global__ __launch_bounds__(256) void k_a0(const float* __restrict__ ne,
                                            float* __restrict__ A0) {
  int gid = blockIdx.x * 256 + threadIdx.x;
  int n = gid >> 11, m = gid & 2047;
  float acc = 0.f;
  #pragma unroll
  for (int d = 0; d < 10; ++d) acc = fmaf(ne[n * 10 + d], ne[m * 10 + d], acc);
  A0[gid] = acc;
}

// ---------------- K2: per-row top-k -> cinv, idx, w ----------------
// One block per node n; A0 row staged in LDS once; each warp serves 4 batches.
__global__ __launch_bounds__(256) void k_topk(const float* __restrict__ A0,
                                              const float* __restrict__ t,
                                              const float* __restrict__ n_t,
                                              const float* __restrict__ p,
                                              float* __restrict__ cinv,
                                              int* __restrict__ idxb,
                                              float* __restrict__ wgt) {
  const int n = blockIdx.x;                 // 2048 blocks
  const int warp = threadIdx.x >> 6, lane = threadIdx.x & 63;

  __shared__ float rowS[2048];              // 8 KiB
  __shared__ float candV[4][128];
  __shared__ int   candM[4][128];

  {
    const float4* src = (const float4*)(A0 + (size_t)n * 2048);
    float4* dst = (float4*)rowS;
    for (int i = threadIdx.x; i < 512; i += 256) dst[i] = src[i];
  }
  __syncthreads();

  // per-lane copy of the row, slot s -> m = (s>>2)*256 + lane*4 + (s&3)
  float a[32];
  #pragma unroll
  for (int j = 0; j < 8; ++j) {
    float4 f = ((const float4*)rowS)[j * 64 + lane];
    a[j * 4 + 0] = f.x; a[j * 4 + 1] = f.y;
    a[j * 4 + 2] = f.z; a[j * 4 + 3] = f.w;
  }

  for (int bi = 0; bi < 4; ++bi) {
    const int b = warp * 4 + bi;
    const int r = (b << 11) | n;

    float at = 0.f;
    #pragma unroll
    for (int d = 0; d < 8; ++d) at = fmaf(n_t[b * 8 + d], t[b * 8 + d], at);
    const float s = 1.0f + 0.3f * (1.0f / (1.0f + expf(-p[b])));

    // lane max of v = relu(s*(a+at))
    float lm = -1.f;
    #pragma unroll
    for (int j = 0; j < 32; ++j) lm = fmaxf(lm, fmaxf(s * (a[j] + at), 0.f));

    // 11th-largest (distinct) lane-max: lower bound on 11th-largest global value
    float last = 3.4e38f;
    for (int rd = 0; rd < 11; ++rd) {
      float x = (lm < last) ? lm : -1.f;
      #pragma unroll
      for (int off = 32; off > 0; off >>= 1) x = fmaxf(x, __shfl_xor(x, off));
      last = x;
    }
    const float T = last - 0.0101f;

    // collect candidates (compaction via ballot prefix)
    int cnt = 0;
    #pragma unroll
    for (int slot = 0; slot < 32; ++slot) {
      float v = fmaxf(s * (a[slot] + at), 0.f);
      bool c = (v >= T);
      unsigned long long mk = __ballot(c);
      if (c) {
        int pos = cnt + __popcll(mk & ((1ull << lane) - 1ull));
        if (pos < 128) {
          candV[warp][pos] = v;
          candM[warp][pos] = ((slot >> 2) << 8) + (lane << 2) + (slot & 3);
        }
      }
      cnt += (int)__popcll(mk);
    }
    int C = cnt < 128 ? cnt : 128;

    // exact top-10 of (pre + noise), tie-break by smaller index (lax.top_k)
    float k0 = -1.f, k1v = -1.f, p0 = 0.f, p1 = 0.f;
    int m0 = 1 << 30, m1 = 1 << 30;
    if (lane < C) {
      p0 = candV[warp][lane]; m0 = candM[warp][lane];
      k0 = p0 + noise_val((unsigned)r * 2048u + (unsigned)m0);
    }
    if (lane + 64 < C) {
      p1 = candV[warp][lane + 64]; m1 = candM[warp][lane + 64];
      k1v = p1 + noise_val((unsigned)r * 2048u + (unsigned)m1);
    }

    float selPre = 0.f; int selIdx = 0;
    for (int ts = 0; ts < 10; ++ts) {
      bool first = (k0 > k1v) || (k0 == k1v && m0 < m1);
      float bk = first ? k0 : k1v; int bm = first ? m0 : m1; float bp = first ? p0 : p1;
      #pragma unroll
      for (int off = 32; off > 0; off >>= 1) {
        float ok = __shfl_xor(bk, off); int om = __shfl_xor(bm, off);
        float op = __shfl_xor(bp, off);
        if (ok > bk || (ok == bk && om < bm)) { bk = ok; bm = om; bp = op; }
      }
      if (lane == ts) { selIdx = bm; selPre = bp; }
      if (m0 == bm) k0 = -1.f;
      if (m1 == bm) k1v = -1.f;
    }

    float e = (lane < 10) ? expf(selPre) : 0.f;
    float sum = e;
    #pragma unroll
    for (int off = 32; off > 0; off >>= 1) sum += __shfl_xor(sum, off);
    float ci = 1.0f / (2038.0f + sum);
    if (lane == 0) cinv[r] = ci;
    if (lane < 10) {
      idxb[r * 10 + lane] = selIdx;
      wgt[r * 10 + lane] = (e - 1.0f) * ci;
    }
  }
}

// ---------------- K3: per-batch column sums [16][32] ----------------
__global__ __launch_bounds__(256) void k_colsum(const float* __restrict__ in,
                                                float* __restrict__ cs) {
  const int b = blockIdx.x, c = threadIdx.x & 31, g = threadIdx.x >> 5;
  double acc = 0.0;
  for (int m = g; m < 2048; m += 8) acc += (double)in[(((b << 11) + m) << 5) + c];
  __shared__ double red[8][32];
  red[g][c] = acc;
  __syncthreads();
  if (g == 0) {
    double s2 = red[0][c];
    #pragma unroll
    for (int i = 1; i < 8; ++i) s2 += red[i][c];
    cs[(b << 5) + c] = (float)s2;
  }
}

// ---------------- K4: Y1 = A@x ----------------
__global__ __launch_bounds__(256) void k_axpy(const float* __restrict__ x,
                                              const float* __restrict__ cinv,
                                              const int* __restrict__ idxb,
                                              const float* __restrict__ wgt,
                                              const float* __restrict__ cs,
                                              float* __restrict__ Y1) {
  int gid = blockIdx.x * 256 + threadIdx.x;
  int r = gid >> 5, c = gid & 31, b = r >> 11;
  float acc = cinv[r] * cs[(b << 5) + c];
  #pragma unroll
  for (int j = 0; j < 10; ++j)
    acc = fmaf(wgt[r * 10 + j], x[(((b << 11) + idxb[r * 10 + j]) << 5) + c], acc);
  Y1[gid] = acc;
}

// ---------------- K5: Y2 = A@Y1 ; build V = [x, Y1, 2*Y2 - x] ----------------
__global__ __launch_bounds__(256) void k_v(const float* __restrict__ x,
                                           const float* __restrict__ Y1,
                                           const float* __restrict__ cinv,
                                           const int* __restrict__ idxb,
                                           const float* __restrict__ wgt,
                                           const float* __restrict__ csy,
                                           float* __restrict__ V) {
  int gid = blockIdx.x * 256 + threadIdx.x;
  int r = gid >> 5, c = gid & 31, b = r >> 11;
  float y2 = cinv[r] * csy[(b << 5) + c];
  #pragma unroll
  for (int j = 0; j < 10; ++j)
    y2 = fmaf(wgt[r * 10 + j], Y1[(((b << 11) + idxb[r * 10 + j]) << 5) + c], y2);
  float xv = x[gid], y1v = Y1[gid];
  V[r * 96 + c] = xv;
  V[r * 96 + 32 + c] = y1v;
  V[r * 96 + 64 + c] = 2.f * y2 - xv;
}

// ---------------- K6: node-term + bias (2 nodes/block, ki-split LDS) ----------------
__global__ __launch_bounds__(256) void k_outn(const float* __restrict__ ne,
                                              const float* __restrict__ n_t,
                                              const float* __restrict__ wp,
                                              const float* __restrict__ bp,
                                              const float* __restrict__ V,
                                              float* __restrict__ out) {
  const int n0 = blockIdx.x * 2;              // 1024 blocks
  __shared__ float Wn[2][48][64];             // 24 KiB (half of ki at a time)
  __shared__ float Vs[2][16][98];             // 12.25 KiB, padded
  __shared__ float bN[2][64];

  for (int e2 = threadIdx.x; e2 < 2 * 16 * 96; e2 += 256) {
    int nn = e2 / 1536, rem = e2 % 1536, bb = rem / 96, ki = rem % 96;
    Vs[nn][bb][ki] = V[((size_t)(bb << 11) + n0 + nn) * 96 + ki];
  }
  for (int e2 = threadIdx.x; e2 < 2 * 64; e2 += 256) {
    int nn = e2 >> 6, o = e2 & 63;
    float acc = 0.f;
    #pragma unroll
    for (int d = 0; d < 10; ++d)
      acc = fmaf(ne[(n0 + nn) * 10 + d], bp[d * 64 + o], acc);
    bN[nn][o] = acc;
  }

  const int wave = threadIdx.x >> 6, lane = threadIdx.x & 63;
  const int nn = wave >> 1, half = wave & 1;
  const int og = lane & 15, bg = lane >> 4;
  const int bA = half * 8 + bg * 2, bB = bA + 1;

  float acc[2][4] = {};
  for (int h = 0; h < 2; ++h) {
    __syncthreads();   // h=0: Vs/bN visible; h=1: previous Wn reads done
    for (int e2 = threadIdx.x; e2 < 2 * 48 * 64; e2 += 256) {
      int nn2 = e2 / 3072, rem = e2 % 3072, ki = rem >> 6, o = rem & 63;
      int kiG = h * 48 + ki;
      float a2 = 0.f;
      #pragma unroll
      for (int d = 0; d < 10; ++d)
        a2 = fmaf(ne[(n0 + nn2) * 10 + d], wp[(d * 96 + kiG) * 64 + o], a2);
      Wn[nn2][ki][o] = a2;
    }
    __syncthreads();
    for (int ki = 0; ki < 48; ++ki) {
      float4 wv = *(const float4*)&Wn[nn][ki][og * 4];
      float vA = Vs[nn][bA][h * 48 + ki], vB = Vs[nn][bB][h * 48 + ki];
      acc[0][0] = fmaf(vA, wv.x, acc[0][0]); acc[0][1] = fmaf(vA, wv.y, acc[0][1]);
      acc[0][2] = fmaf(vA, wv.z, acc[0][2]); acc[0][3] = fmaf(vA, wv.w, acc[0][3]);
      acc[1][0] = fmaf(vB, wv.x, acc[1][0]); acc[1][1] = fmaf(vB, wv.y, acc[1][1]);
      acc[1][2] = fmaf(vB, wv.z, acc[1][2]); acc[1][3] = fmaf(vB, wv.w, acc[1][3]);
    }
  }

  const int n = n0 + nn;
  #pragma unroll
  for (int i = 0; i < 2; ++i) {
    int b = (i == 0) ? bA : bB;
    float4 res;
    #pragma unroll
    for (int q = 0; q < 4; ++q) {
      int o = og * 4 + q;
      float bT = 0.f;
      #pragma unroll
      for (int d = 0; d < 8; ++d)
        bT = fmaf(n_t[b * 8 + d], bp[(10 + d) * 64 + o], bT);
      (&res.x)[q] = acc[i][q] + bN[nn][o] + bT;
    }
    *(float4*)&out[((size_t)(b << 11) + n) * 64 + og * 4] = res;
  }
}

// ---------------- K7: temporal-term  out += V @ Wt[b] ----------------
// 512 blocks (16 b x 32 tiles of 64 rows), 512 threads, 8 rows/wave.
__global__ __launch_bounds__(512) void k_outt(const float* __restrict__ n_t,
                                              const float* __restrict__ wp,
                                              const float* __restrict__ V,
                                              float* __restrict__ out) {
  const int b = blockIdx.x >> 5, tile = blockIdx.x & 31;
  __shared__ float Wt[96][64];                // 24 KiB
  for (int e2 = threadIdx.x; e2 < 96 * 64; e2 += 512) {
    int ki = e2 >> 6, o = e2 & 63;
    float acc = 0.f;
    #pragma unroll
    for (int d = 0; d < 8; ++d)
      acc = fmaf(n_t[b * 8 + d], wp[((10 + d) * 96 + ki) * 64 + o], acc);
    Wt[ki][o] = acc;
  }
  __syncthreads();
  const int wave = threadIdx.x >> 6, lane = threadIdx.x & 63;
  const int og = lane & 15, rg = lane >> 4;
  const int r0 = tile * 64 + wave * 8 + rg * 2;

  float acc[2][4] = {};
  for (int ki4 = 0; ki4 < 24; ++ki4) {
    float4 vv[2];
    #pragma unroll
    for (int i = 0; i < 2; ++i)
      vv[i] = *(const float4*)&V[(size_t)((b << 11) + r0 + i) * 96 + ki4 * 4];
    #pragma unroll
    for (int t2 = 0; t2 < 4; ++t2) {
      float4 wv = *(const float4*)&Wt[ki4 * 4 + t2][og * 4];
      #pragma unroll
      for (int i = 0; i < 2; ++i) {
        float vi = (t2 == 0) ? vv[i].x : (t2 == 1) ? vv[i].y
                 : (t2 == 2) ? vv[i].z : vv[i].w;
        acc[i][0] = fmaf(vi, wv.x, acc[i][0]);
        acc[i][1] = fmaf(vi, wv.y, acc[i][1]);
        acc[i][2] = fmaf(vi, wv.z, acc[i][2]);
        acc[i][3] = fmaf(vi, wv.w, acc[i][3]);
      }
    }
  }
  #pragma unroll
  for (int i = 0; i < 2; ++i) {
    size_t oidx = (size_t)((b << 11) + r0 + i) * 64 + og * 4;
    float4 cur = *(float4*)&out[oidx];
    cur.x += acc[i][0]; cur.y += acc[i][1];
    cur.z += acc[i][2]; cur.w += acc[i][3];
    *(float4*)&out[oidx] = cur;
  }
}

extern "C" void kernel_launch(void* const* d_in, const int* in_sizes, int n_in,
                              void* d_out, int out_size, void* d_ws, size_t ws_size,
                              hipStream_t stream) {
  const float* x   = (const float*)d_in[0];
  const float* ne  = (const float*)d_in[1];
  const float* t   = (const float*)d_in[2];
  const float* n_t = (const float*)d_in[3];
  const float* p   = (const float*)d_in[4];
  const float* wp  = (const float*)d_in[5];
  const float* bp  = (const float*)d_in[6];
  float* out = (float*)d_out;

  float* ws   = (float*)d_ws;
  float* A0   = ws;                         // 4,194,304
  float* cinv = A0 + 4194304;               // 32,768
  int*   idxb = (int*)(cinv + 32768);       // 327,680
  float* wgt  = (float*)(idxb + 327680);    // 327,680
  float* csx  = wgt + 327680;               // 512
  float* csy  = csx + 512;                  // 512
  float* Y1   = csy + 512;                  // 1,048,576
  float* V    = Y1 + 1048576;               // 3,145,728

  k_a0    <<<16384, 256, 0, stream>>>(ne, A0);
  k_topk  <<<2048, 256, 0, stream>>>(A0, t, n_t, p, cinv, idxb, wgt);
  k_colsum<<<16, 256, 0, stream>>>(x, csx);
  k_axpy  <<<4096, 256, 0, stream>>>(x, cinv, idxb, wgt, csx, Y1);
  k_colsum<<<16, 256, 0, stream>>>(Y1, csy);
  k_v     <<<4096, 256, 0, stream>>>(x, Y1, cinv, idxb, wgt, csy, V);
  k_outn  <<<1024, 256, 0, stream>>>(ne, n_t, wp, bp, V, out);
  k_outt  <<<512, 512, 0, stream>>>(n_t, wp, V, out);
}

// Round 4
// 202.496 us; speedup vs baseline: 2.8027x; 1.9759x over previous
//
#include <hip/hip_runtime.h>
#include <hip/hip_bf16.h>

// TGCN fused pipeline for MI355X (gfx950).
//  * A = softmax(pre*mask) = c_n*1^T + sparse(10/row)  ->  all graph convs are
//    O(N*TOPK*C) via colsum + 10-term gathers. No N^3 anywhere.
//  * Exact Threefry-2x32 replication of jax.random.uniform(key(42)) noise so
//    top-k tie-breaks match the reference bit-for-bit (verified r1/r2).
//  * pre = relu(s_b*(a+at_b)), s_b>=1  =>  pre-order == a-order. Candidate
//    discovery (bound + compaction) hoisted to once-per-node in a-space with
//    the same 0.0101 margin. Selection = LDS rank-count on packed u64 keys
//    (key desc, idx asc) -- same top-10 SET, order-free downstream.
// R3 changes: k_topk restructured (was ds_bpermute-pipe-bound, 117us: 250
//             shfl/batch -> 6); colsum 2-stage (16 -> 256+1 blocks).
// R4: identical resubmit (R3 bench was GPUAcquisitionTimeout, never ran).

constexpr int BS = 16, NN_ = 2048, CIN = 32, OUT = 64, TK = 10;
constexpr int ROWS = BS * NN_;

// ---------------- Threefry-2x32 (matches jax._src.prng) ----------------
__device__ __forceinline__ void tf2x32(unsigned x0, unsigned x1,
                                       unsigned& o0, unsigned& o1) {
  const unsigned k0 = 0u, k1 = 42u;
  const unsigned ks2 = k0 ^ k1 ^ 0x1BD11BDAu;
#define TF_R(rot) { x0 += x1; x1 = (x1 << rot) | (x1 >> (32 - rot)); x1 ^= x0; }
  x0 += k0; x1 += k1;
  TF_R(13) TF_R(15) TF_R(26) TF_R(6)
  x0 += k1; x1 += ks2 + 1u;
  TF_R(17) TF_R(29) TF_R(16) TF_R(24)
  x0 += ks2; x1 += k0 + 2u;
  TF_R(13) TF_R(15) TF_R(26) TF_R(6)
  x0 += k0; x1 += k1 + 3u;
  TF_R(17) TF_R(29) TF_R(16) TF_R(24)
  x0 += k1; x1 += ks2 + 4u;
  TF_R(13) TF_R(15) TF_R(26) TF_R(6)
  x0 += ks2; x1 += k0 + 5u;
#undef TF_R
  o0 = x0; o1 = x1;
}

__device__ __forceinline__ float noise_val(unsigned flat) {
  unsigned o0, o1; tf2x32(0u, flat, o0, o1);
  unsigned bits = o0 ^ o1;
  float u = __uint_as_float((bits >> 9) | 0x3f800000u) - 1.0f;
  return 0.01f * u;
}

// ---------------- K1: A0 = node_emb @ node_emb^T ----------------
__global__ __launch_bounds__(256) void k_a0(const float* __restrict__ ne,
                                            float* __restrict__ A0) {
  int gid = blockIdx.x * 256 + threadIdx.x;
  int n = gid >> 11, m = gid & 2047;
  float acc = 0.f;
  #pragma unroll
  for (int d = 0; d < 10; ++d) acc = fmaf(ne[n * 10 + d], ne[m * 10 + d], acc);
  A0[gid] = acc;
}

// ---------------- K2: per-row top-k -> cinv, idx, w ----------------
// 2 nodes/block; warps {0,1}->node0, {2,3}->node1; each warp: 8 batches.
// Phase A (per node, in a-space): 11-round lower bound + ballot compaction.
// Phase B (per batch): keys = pre+noise for <=C candidates, LDS rank select.
__global__ __launch_bounds__(256) void k_topk(const float* __restrict__ A0,
                                              const float* __restrict__ t,
                                              const float* __restrict__ n_t,
                                              const float* __restrict__ p,
                                              float* __restrict__ cinv,
                                              int* __restrict__ idxb,
                                              float* __restrict__ wgt) {
  const int n0 = blockIdx.x * 2;                  // 1024 blocks
  const int warp = threadIdx.x >> 6, lane = threadIdx.x & 63;
  const int ln = warp >> 1;                       // local node
  const int n = n0 + ln;
  const int bh = (warp & 1) * 8;                  // batch half

  __shared__ float rowS[2][2048];                 // 16 KiB
  __shared__ float candA[4][128];                 // 2 KiB (per-warp slices)
  __shared__ int   candM[4][128];                 // 2 KiB
  __shared__ unsigned long long keyS[4][128];     // 4 KiB

  {
    const float4* src = (const float4*)(A0 + (size_t)n0 * 2048);
    float4* dst = (float4*)rowS;
    for (int i = threadIdx.x; i < 1024; i += 256) dst[i] = src[i];
  }
  __syncthreads();

  // per-lane slots: slot s -> m = (s>>2)*256 + lane*4 + (s&3)
  float a[32];
  #pragma unroll
  for (int j = 0; j < 8; ++j) {
    float4 f = ((const float4*)rowS[ln])[j * 64 + lane];
    a[j * 4 + 0] = f.x; a[j * 4 + 1] = f.y;
    a[j * 4 + 2] = f.z; a[j * 4 + 3] = f.w;
  }

  // lane max
  float lm = -3.4e38f;
  #pragma unroll
  for (int j = 0; j < 32; ++j) lm = fmaxf(lm, a[j]);

  // 11th-largest distinct lane-max: lower bound on 11th-largest row value
  float last = 3.4e38f;
  for (int rd = 0; rd < 11; ++rd) {
    float x = (lm < last) ? lm : -3.4e38f;
    #pragma unroll
    for (int off = 32; off > 0; off >>= 1) x = fmaxf(x, __shfl_xor(x, off));
    last = x;
  }
  const float T = last - 0.0101f;   // a-space margin (s_b >= 1)

  // compact candidates (a >= T) into this warp's LDS slice
  int cnt = 0;
  #pragma unroll
  for (int slot = 0; slot < 32; ++slot) {
    bool c = (a[slot] >= T);
    unsigned long long mk = __ballot(c);
    if (c) {
      int pos = cnt + __popcll(mk & ((1ull << lane) - 1ull));
      if (pos < 128) {
        candA[warp][pos] = a[slot];
        candM[warp][pos] = ((slot >> 2) << 8) + (lane << 2) + (slot & 3);
      }
    }
    cnt += (int)__popcll(mk);
  }
  const int C = cnt < 128 ? cnt : 128;
  const bool two = (C > 64);                      // wave-uniform

  __syncthreads();  // own-warp LDS write->read; barrier for safety (uniform)

  float a0c = 0.f, a1c = 0.f; int m0 = 0, m1 = 0;
  if (lane < C) { a0c = candA[warp][lane]; m0 = candM[warp][lane]; }
  if (two && lane + 64 < C) { a1c = candA[warp][lane + 64]; m1 = candM[warp][lane + 64]; }

  for (int bi = 0; bi < 8; ++bi) {
    const int b = bh + bi;
    const int r = (b << 11) | n;

    float at = 0.f;
    #pragma unroll
    for (int d = 0; d < 8; ++d) at = fmaf(n_t[b * 8 + d], t[b * 8 + d], at);
    const float s = 1.0f + 0.3f * (1.0f / (1.0f + expf(-p[b])));

    // keys
    float pre0 = fmaxf(s * (a0c + at), 0.f);
    unsigned long long k0 = 0ull;
    if (lane < C) {
      float key0 = pre0 + noise_val((unsigned)r * 2048u + (unsigned)m0);
      k0 = ((unsigned long long)__float_as_uint(key0) << 32) |
           (unsigned)(2047 - m0);
      keyS[warp][lane] = k0;
    }
    float pre1 = 0.f;
    unsigned long long k1 = 0ull;
    if (two) {
      if (lane + 64 < C) {
        pre1 = fmaxf(s * (a1c + at), 0.f);
        float key1 = pre1 + noise_val((unsigned)r * 2048u + (unsigned)m1);
        k1 = ((unsigned long long)__float_as_uint(key1) << 32) |
             (unsigned)(2047 - m1);
      }
      keyS[warp][lane + 64] = k1;
    }
    __syncthreads();  // block-uniform; own-warp slice visibility

    // rank within candidates == global rank for top-10 members
    int rank0 = 0, rank1 = 0;
    for (int j2 = 0; j2 < C; ++j2) {
      unsigned long long kj = keyS[warp][j2];
      rank0 += (kj > k0) ? 1 : 0;
      if (two) rank1 += (kj > k1) ? 1 : 0;
    }
    bool w0 = (lane < C) && (rank0 < 10);
    bool w1 = two && (lane + 64 < C) && (rank1 < 10);

    float e0 = w0 ? expf(pre0) : 0.f;
    float e1 = w1 ? expf(pre1) : 0.f;
    float sum = e0 + e1;
    #pragma unroll
    for (int off = 32; off > 0; off >>= 1) sum += __shfl_xor(sum, off);
    const float ci = 1.0f / (2038.0f + sum);

    unsigned long long mk0 = __ballot(w0);
    if (w0) {
      int pos = __popcll(mk0 & ((1ull << lane) - 1ull));
      idxb[r * 10 + pos] = m0;
      wgt[r * 10 + pos] = (e0 - 1.0f) * ci;
    }
    if (two) {
      unsigned long long mk1 = __ballot(w1);
      int base = __popcll(mk0);
      if (w1) {
        int pos = base + __popcll(mk1 & ((1ull << lane) - 1ull));
        idxb[r * 10 + pos] = m1;
        wgt[r * 10 + pos] = (e1 - 1.0f) * ci;
      }
    }
    if (lane == 0) cinv[r] = ci;
    __syncthreads();
  }
}

// ---------------- K3a: partial column sums [16][16 chunks][32] ----------------
__global__ __launch_bounds__(256) void k_colsum_p(const float* __restrict__ in,
                                                  double* __restrict__ part) {
  const int b = blockIdx.x >> 4, ch = blockIdx.x & 15;   // 256 blocks
  const int c = threadIdx.x & 31, g = threadIdx.x >> 5;
  double acc = 0.0;
  for (int m = ch * 128 + g; m < ch * 128 + 128; m += 8)
    acc += (double)in[(((b << 11) + m) << 5) + c];
  __shared__ double red[8][32];
  red[g][c] = acc;
  __syncthreads();
  if (g == 0) {
    double s2 = red[0][c];
    #pragma unroll
    for (int i = 1; i < 8; ++i) s2 += red[i][c];
    part[(((b << 4) + ch) << 5) + c] = s2;
  }
}

// ---------------- K3b: finalize column sums [16][32] ----------------
__global__ __launch_bounds__(512) void k_colsum_f(const double* __restrict__ part,
                                                  float* __restrict__ cs) {
  const int b = threadIdx.x >> 5, c = threadIdx.x & 31;  // 1 block, 512 thr
  double s2 = 0.0;
  #pragma unroll
  for (int ch = 0; ch < 16; ++ch) s2 += part[(((b << 4) + ch) << 5) + c];
  cs[(b << 5) + c] = (float)s2;
}

// ---------------- K4: Y1 = A@x ----------------
__global__ __launch_bounds__(256) void k_axpy(const float* __restrict__ x,
                                              const float* __restrict__ cinv,
                                              const int* __restrict__ idxb,
                                              const float* __restrict__ wgt,
                                              const float* __restrict__ cs,
                                              float* __restrict__ Y1) {
  int gid = blockIdx.x * 256 + threadIdx.x;
  int r = gid >> 5, c = gid & 31, b = r >> 11;
  float acc = cinv[r] * cs[(b << 5) + c];
  #pragma unroll
  for (int j = 0; j < 10; ++j)
    acc = fmaf(wgt[r * 10 + j], x[(((b << 11) + idxb[r * 10 + j]) << 5) + c], acc);
  Y1[gid] = acc;
}

// ---------------- K5: Y2 = A@Y1 ; build V = [x, Y1, 2*Y2 - x] ----------------
__global__ __launch_bounds__(256) void k_v(const float* __restrict__ x,
                                           const float* __restrict__ Y1,
                                           const float* __restrict__ cinv,
                                           const int* __restrict__ idxb,
                                           const float* __restrict__ wgt,
                                           const float* __restrict__ csy,
                                           float* __restrict__ V) {
  int gid = blockIdx.x * 256 + threadIdx.x;
  int r = gid >> 5, c = gid & 31, b = r >> 11;
  float y2 = cinv[r] * csy[(b << 5) + c];
  #pragma unroll
  for (int j = 0; j < 10; ++j)
    y2 = fmaf(wgt[r * 10 + j], Y1[(((b << 11) + idxb[r * 10 + j]) << 5) + c], y2);
  float xv = x[gid], y1v = Y1[gid];
  V[r * 96 + c] = xv;
  V[r * 96 + 32 + c] = y1v;
  V[r * 96 + 64 + c] = 2.f * y2 - xv;
}

// ---------------- K6: node-term + bias (2 nodes/block, ki-split LDS) ----------------
__global__ __launch_bounds__(256) void k_outn(const float* __restrict__ ne,
                                              const float* __restrict__ n_t,
                                              const float* __restrict__ wp,
                                              const float* __restrict__ bp,
                                              const float* __restrict__ V,
                                              float* __restrict__ out) {
  const int n0 = blockIdx.x * 2;              // 1024 blocks
  __shared__ float Wn[2][48][64];             // 24 KiB
  __shared__ float Vs[2][16][98];             // 12.25 KiB, padded
  __shared__ float bN[2][64];

  for (int e2 = threadIdx.x; e2 < 2 * 16 * 96; e2 += 256) {
    int nn = e2 / 1536, rem = e2 % 1536, bb = rem / 96, ki = rem % 96;
    Vs[nn][bb][ki] = V[((size_t)(bb << 11) + n0 + nn) * 96 + ki];
  }
  for (int e2 = threadIdx.x; e2 < 2 * 64; e2 += 256) {
    int nn = e2 >> 6, o = e2 & 63;
    float acc = 0.f;
    #pragma unroll
    for (int d = 0; d < 10; ++d)
      acc = fmaf(ne[(n0 + nn) * 10 + d], bp[d * 64 + o], acc);
    bN[nn][o] = acc;
  }

  const int wave = threadIdx.x >> 6, lane = threadIdx.x & 63;
  const int nn = wave >> 1, half = wave & 1;
  const int og = lane & 15, bg = lane >> 4;
  const int bA = half * 8 + bg * 2, bB = bA + 1;

  float acc[2][4] = {};
  for (int h = 0; h < 2; ++h) {
    __syncthreads();
    for (int e2 = threadIdx.x; e2 < 2 * 48 * 64; e2 += 256) {
      int nn2 = e2 / 3072, rem = e2 % 3072, ki = rem >> 6, o = rem & 63;
      int kiG = h * 48 + ki;
      float a2 = 0.f;
      #pragma unroll
      for (int d = 0; d < 10; ++d)
        a2 = fmaf(ne[(n0 + nn2) * 10 + d], wp[(d * 96 + kiG) * 64 + o], a2);
      Wn[nn2][ki][o] = a2;
    }
    __syncthreads();
    for (int ki = 0; ki < 48; ++ki) {
      float4 wv = *(const float4*)&Wn[nn][ki][og * 4];
      float vA = Vs[nn][bA][h * 48 + ki], vB = Vs[nn][bB][h * 48 + ki];
      acc[0][0] = fmaf(vA, wv.x, acc[0][0]); acc[0][1] = fmaf(vA, wv.y, acc[0][1]);
      acc[0][2] = fmaf(vA, wv.z, acc[0][2]); acc[0][3] = fmaf(vA, wv.w, acc[0][3]);
      acc[1][0] = fmaf(vB, wv.x, acc[1][0]); acc[1][1] = fmaf(vB, wv.y, acc[1][1]);
      acc[1][2] = fmaf(vB, wv.z, acc[1][2]); acc[1][3] = fmaf(vB, wv.w, acc[1][3]);
    }
  }

  const int n = n0 + nn;
  #pragma unroll
  for (int i = 0; i < 2; ++i) {
    int b = (i == 0) ? bA : bB;
    float4 res;
    #pragma unroll
    for (int q = 0; q < 4; ++q) {
      int o = og * 4 + q;
      float bT = 0.f;
      #pragma unroll
      for (int d = 0; d < 8; ++d)
        bT = fmaf(n_t[b * 8 + d], bp[(10 + d) * 64 + o], bT);
      (&res.x)[q] = acc[i][q] + bN[nn][o] + bT;
    }
    *(float4*)&out[((size_t)(b << 11) + n) * 64 + og * 4] = res;
  }
}

// ---------------- K7: temporal-term  out += V @ Wt[b] ----------------
__global__ __launch_bounds__(512) void k_outt(const float* __restrict__ n_t,
                                              const float* __restrict__ wp,
                                              const float* __restrict__ V,
                                              float* __restrict__ out) {
  const int b = blockIdx.x >> 5, tile = blockIdx.x & 31;   // 512 blocks
  __shared__ float Wt[96][64];
  for (int e2 = threadIdx.x; e2 < 96 * 64; e2 += 512) {
    int ki = e2 >> 6, o = e2 & 63;
    float acc = 0.f;
    #pragma unroll
    for (int d = 0; d < 8; ++d)
      acc = fmaf(n_t[b * 8 + d], wp[((10 + d) * 96 + ki) * 64 + o], acc);
    Wt[ki][o] = acc;
  }
  __syncthreads();
  const int wave = threadIdx.x >> 6, lane = threadIdx.x & 63;
  const int og = lane & 15, rg = lane >> 4;
  const int r0 = tile * 64 + wave * 8 + rg * 2;

  float acc[2][4] = {};
  for (int ki4 = 0; ki4 < 24; ++ki4) {
    float4 vv[2];
    #pragma unroll
    for (int i = 0; i < 2; ++i)
      vv[i] = *(const float4*)&V[(size_t)((b << 11) + r0 + i) * 96 + ki4 * 4];
    #pragma unroll
    for (int t2 = 0; t2 < 4; ++t2) {
      float4 wv = *(const float4*)&Wt[ki4 * 4 + t2][og * 4];
      #pragma unroll
      for (int i = 0; i < 2; ++i) {
        float vi = (t2 == 0) ? vv[i].x : (t2 == 1) ? vv[i].y
                 : (t2 == 2) ? vv[i].z : vv[i].w;
        acc[i][0] = fmaf(vi, wv.x, acc[i][0]);
        acc[i][1] = fmaf(vi, wv.y, acc[i][1]);
        acc[i][2] = fmaf(vi, wv.z, acc[i][2]);
        acc[i][3] = fmaf(vi, wv.w, acc[i][3]);
      }
    }
  }
  #pragma unroll
  for (int i = 0; i < 2; ++i) {
    size_t oidx = (size_t)((b << 11) + r0 + i) * 64 + og * 4;
    float4 cur = *(float4*)&out[oidx];
    cur.x += acc[i][0]; cur.y += acc[i][1];
    cur.z += acc[i][2]; cur.w += acc[i][3];
    *(float4*)&out[oidx] = cur;
  }
}

extern "C" void kernel_launch(void* const* d_in, const int* in_sizes, int n_in,
                              void* d_out, int out_size, void* d_ws, size_t ws_size,
                              hipStream_t stream) {
  const float* x   = (const float*)d_in[0];
  const float* ne  = (const float*)d_in[1];
  const float* t   = (const float*)d_in[2];
  const float* n_t = (const float*)d_in[3];
  const float* p   = (const float*)d_in[4];
  const float* wp  = (const float*)d_in[5];
  const float* bp  = (const float*)d_in[6];
  float* out = (float*)d_out;

  float* ws   = (float*)d_ws;
  float* A0   = ws;                         // 4,194,304
  float* cinv = A0 + 4194304;               // 32,768
  int*   idxb = (int*)(cinv + 32768);       // 327,680
  float* wgt  = (float*)(idxb + 327680);    // 327,680
  float* csx  = wgt + 327680;               // 512
  float* csy  = csx + 512;                  // 512
  float* Y1   = csy + 512;                  // 1,048,576
  float* V    = Y1 + 1048576;               // 3,145,728
  double* partX = (double*)(V + 3145728);   // 8,192 doubles (8B-aligned)
  double* partY = partX + 8192;             // 8,192 doubles

  k_a0      <<<16384, 256, 0, stream>>>(ne, A0);
  k_topk    <<<1024, 256, 0, stream>>>(A0, t, n_t, p, cinv, idxb, wgt);
  k_colsum_p<<<256, 256, 0, stream>>>(x, partX);
  k_colsum_f<<<1, 512, 0, stream>>>(partX, csx);
  k_axpy    <<<4096, 256, 0, stream>>>(x, cinv, idxb, wgt, csx, Y1);
  k_colsum_p<<<256, 256, 0, stream>>>(Y1, partY);
  k_colsum_f<<<1, 512, 0, stream>>>(partY, csy);
  k_v       <<<4096, 256, 0, stream>>>(x, Y1, cinv, idxb, wgt, csy, V);
  k_outn    <<<1024, 256, 0, stream>>>(ne, n_t, wp, bp, V, out);
  k_outt    <<<512, 512, 0, stream>>>(n_t, wp, V, out);
}